// Round 8
// baseline (96.768 us; speedup 1.0000x reference)
//
#include <hip/hip_runtime.h>
#include <hip/hip_bf16.h>

#define N 8192
#define FIN 128
#define FOUT 64
#define CSPLIT 2
#define CHUNK (N / CSPLIT)     // 4096 cols per block
#define M 32                   // rows per block
#define TILE 128               // cols per whT tile
#define NT (CHUNK / TILE)      // 32 tiles

typedef __attribute__((ext_vector_type(4))) float f32x4;
typedef __attribute__((ext_vector_type(4))) int i32x4;
typedef __attribute__((ext_vector_type(8))) short bf16x8;

#define GLOAD_LDS16(gp, lp)                                                    \
    __builtin_amdgcn_global_load_lds(                                          \
        (const __attribute__((address_space(1))) void*)(gp),                   \
        (__attribute__((address_space(3))) void*)(lp), 16, 0, 0)

__device__ __forceinline__ short f2bf(float x) {
    __hip_bfloat16 b = __float2bfloat16(x);
    union { __hip_bfloat16 b; short s; } u; u.b = b; return u.s;
}

// Kernel 0: pack adj (0/1 int32) into bits: pk[row][wi ^ (row&7)] covers cols
// [wi*32, wi*32+32), bit b = col wi*32+b. Pure streaming: 268 MB -> 8 MB.
__global__ __launch_bounds__(256) void pack_kernel(
    const int* __restrict__ adj, unsigned int* __restrict__ pk) {
    const int w = threadIdx.x >> 6, lane = threadIdx.x & 63;
    const int gw = blockIdx.x * 4 + w;            // 8192 waves
#pragma unroll 4
    for (int it = 0; it < 32; ++it) {
        const int task = it * 8192 + gw;          // (row, 256-col group)
        const int rr = task >> 5;
        const int gg = task & 31;
        i32x4 v = *(const i32x4*)(adj + (size_t)rr * N + gg * 256 + lane * 4);
        unsigned nib = (v[0] != 0 ? 1u : 0u) | (v[1] != 0 ? 2u : 0u) |
                       (v[2] != 0 ? 4u : 0u) | (v[3] != 0 ? 8u : 0u);
        unsigned u;
        u = (unsigned)__shfl_xor((int)nib, 1, 64); nib |= u << 4;   // 8 bits @ lane%2==0
        u = (unsigned)__shfl_xor((int)nib, 2, 64); nib |= u << 8;   // 16 bits @ lane%4==0
        u = (unsigned)__shfl_xor((int)nib, 4, 64); nib |= u << 16;  // 32 bits @ lane%8==0
        if ((lane & 7) == 0) {
            const int wi = gg * 8 + (lane >> 3);
            pk[(size_t)rr * 256 + (wi ^ (rr & 7))] = nib;
        }
    }
}

// Kernel 1: Wh = h @ W (W staged in LDS), s_src = Wh@a1, s_dst = Wh@a2
__global__ __launch_bounds__(256) void wh_kernel(
    const float* __restrict__ h, const float* __restrict__ W,
    const float* __restrict__ a,
    __hip_bfloat16* __restrict__ whT, float* __restrict__ s_src,
    float* __restrict__ s_dst) {
    __shared__ float Wl[FIN * FOUT];              // 32 KB
    const int w = threadIdx.x >> 6;
    const int lane = threadIdx.x & 63;            // lane = output feature f
#pragma unroll
    for (int q = 0; q < 8; ++q) {
        const int i = w * 8 + q;                  // 32 chunks of 256 floats
        GLOAD_LDS16(W + i * 256 + lane * 4, &Wl[i * 256]);
    }
    asm volatile("s_waitcnt vmcnt(0)" ::: "memory");
    __syncthreads();

    const int row = blockIdx.x * 4 + w;
    const float* hr = h + (size_t)row * FIN;
    float acc = 0.f;
#pragma unroll
    for (int k0 = 0; k0 < FIN; k0 += 4) {
        f32x4 hv = *(const f32x4*)(hr + k0);      // wave-uniform -> broadcast
        acc += hv[0] * Wl[(k0 + 0) * FOUT + lane];
        acc += hv[1] * Wl[(k0 + 1) * FOUT + lane];
        acc += hv[2] * Wl[(k0 + 2) * FOUT + lane];
        acc += hv[3] * Wl[(k0 + 3) * FOUT + lane];
    }
    whT[(size_t)lane * N + row] = __float2bfloat16(acc);
    float s1 = acc * a[lane];
    float s2 = acc * a[FOUT + lane];
#pragma unroll
    for (int mm = 32; mm >= 1; mm >>= 1) {
        s1 += __shfl_xor(s1, mm, 64);
        s2 += __shfl_xor(s2, mm, 64);
    }
    if (lane == 0) { s_src[row] = s1; s_dst[row] = s2; }
}

// Kernel 2: fused masked-softmax attention partials. adj comes from the packed
// bit table (16 KB/block LDS, loaded once). whT tiles double-buffered via
// global_load_lds with counted vmcnt (R7 structure, verified).
__global__ __launch_bounds__(512, 4) void gat_partial(
    const unsigned int* __restrict__ pkg, const __hip_bfloat16* __restrict__ whT,
    const float* __restrict__ s_src, const float* __restrict__ s_dst,
    float* __restrict__ numP, float* __restrict__ denP) {
    union SMem {
        struct {
            unsigned int pkl[M][CHUNK / 32];  // 16 KB (bit table, pre-swizzled)
            float sdl[CHUNK];                 // 16 KB
            short whb[2][FOUT][TILE];         // 32 KB (swizzled rows of 256B)
        } s;                                  // 64 KB
        struct { float pC[4][M][FOUT]; float pD[4][M]; } e;  // 33 KB
    };
    __shared__ SMem sm;

    const int tid = threadIdx.x;
    const int w = tid >> 6, lane = tid & 63;
    const int m = lane & 15, kg = lane >> 4;
    const int wr = w >> 2, wc = w & 3;
    const int rg = blockIdx.x >> 1;
    const int c = blockIdx.x & 1;
    const int ibase = rg * M;
    const int cb = c * CHUNK;
    const int aRow = wr * 16 + m;
    const float ssrc = s_src[ibase + aRow];
    const int sidx = w * 2;

    f32x4 acc[4] = {{0,0,0,0},{0,0,0,0},{0,0,0,0},{0,0,0,0}};
    float dsum = 0.f;

    // stage whT tile t into buf: 2 instrs/wave (R7 layout+swizzle, verified)
    auto stageWh = [&](int t, int buf) {
        const int gcol = cb + t * TILE;
#pragma unroll
        for (int q = 0; q < 2; ++q) {
            const int idx = sidx + q;
            const int f = idx * 4 + (lane >> 4);
            const int b = ((lane & 15) * 16) ^ ((f & 15) << 4);
            GLOAD_LDS16(whT + (size_t)f * N + gcol + (b >> 1),
                        &sm.s.whb[buf][idx * 4][0]);
        }
    };

    // prologue: pk chunk (2/wave) + sdl chunk (2/wave) + wh tiles 0,1 (2+2/wave)
#pragma unroll
    for (int q = 0; q < 2; ++q) {
        const int i = sidx + q;                   // 16 chunks of 1 KB
        const int r = 2 * i + (lane >> 5);
        GLOAD_LDS16(pkg + (size_t)(ibase + r) * 256 + c * 128 + (lane & 31) * 4,
                    &sm.s.pkl[2 * i][0]);
    }
#pragma unroll
    for (int q = 0; q < 2; ++q) {
        const int i = sidx + q;
        GLOAD_LDS16(s_dst + cb + i * 256 + lane * 4, &sm.s.sdl[i * 256]);
    }
    stageWh(0, 0);
    stageWh(1, 1);
    asm volatile("s_waitcnt vmcnt(2)" ::: "memory");   // pk+sdl+tile0 done
    __builtin_amdgcn_s_barrier();

#pragma unroll 2
    for (int t = 0; t < NT; ++t) {
        const int buf = t & 1;
        {
            const int kcol = wc * 32 + kg * 8;
            const unsigned int pw = sm.s.pkl[aRow][(t * 4 + wc) ^ (aRow & 7)];
            const unsigned int tq = (pw >> (kg * 8)) & 0xffu;
            f32x4 d0 = *(const f32x4*)&sm.s.sdl[t * TILE + kcol];
            f32x4 d1 = *(const f32x4*)&sm.s.sdl[t * TILE + kcol + 4];
            const char* whbase = (const char*)&sm.s.whb[buf][0][0];
            bf16x8 bq0 = *(const bf16x8*)(whbase + (0 * 16 + m) * 256 + ((kcol * 2) ^ (m << 4)));
            bf16x8 bq1 = *(const bf16x8*)(whbase + (1 * 16 + m) * 256 + ((kcol * 2) ^ (m << 4)));
            bf16x8 bq2 = *(const bf16x8*)(whbase + (2 * 16 + m) * 256 + ((kcol * 2) ^ (m << 4)));
            bf16x8 bq3 = *(const bf16x8*)(whbase + (3 * 16 + m) * 256 + ((kcol * 2) ^ (m << 4)));

            bf16x8 afr;
#pragma unroll
            for (int e = 0; e < 4; ++e) {
                float x = ssrc + d0[e];
                x = (x >= 0.f) ? x : 0.2f * x;
                float p = ((tq >> e) & 1u) ? __expf(x) : 0.f;
                dsum += p;
                afr[e] = f2bf(p);
            }
#pragma unroll
            for (int e = 0; e < 4; ++e) {
                float x = ssrc + d1[e];
                x = (x >= 0.f) ? x : 0.2f * x;
                float p = ((tq >> (4 + e)) & 1u) ? __expf(x) : 0.f;
                dsum += p;
                afr[4 + e] = f2bf(p);
            }

            acc[0] = __builtin_amdgcn_mfma_f32_16x16x32_bf16(afr, bq0, acc[0], 0, 0, 0);
            acc[1] = __builtin_amdgcn_mfma_f32_16x16x32_bf16(afr, bq1, acc[1], 0, 0, 0);
            acc[2] = __builtin_amdgcn_mfma_f32_16x16x32_bf16(afr, bq2, acc[2], 0, 0, 0);
            acc[3] = __builtin_amdgcn_mfma_f32_16x16x32_bf16(afr, bq3, acc[3], 0, 0, 0);
        }

        __builtin_amdgcn_s_barrier();             // all waves done with buf
        if (t + 2 < NT) {
            stageWh(t + 2, buf);
            asm volatile("s_waitcnt vmcnt(2)" ::: "memory");  // tile t+1 ready
            __builtin_amdgcn_s_barrier();
        } else if (t + 1 < NT) {
            asm volatile("s_waitcnt vmcnt(0)" ::: "memory");
            __builtin_amdgcn_s_barrier();
        }
    }

    // denominator: lanes l, l^16, l^32, l^48 share row m
    dsum += __shfl_xor(dsum, 16, 64);
    dsum += __shfl_xor(dsum, 32, 64);

    // epilogue (last barrier passed -> safe to reuse LDS)
#pragma unroll
    for (int r = 0; r < 4; ++r) {
#pragma unroll
        for (int q = 0; q < 4; ++q) {
            sm.e.pC[wc][wr * 16 + kg * 4 + r][q * 16 + m] = acc[q][r];
        }
    }
    if (kg == 0) sm.e.pD[wc][wr * 16 + m] = dsum;
    __syncthreads();

    float* numC = numP + (size_t)c * N * FOUT;
    float* denC = denP + (size_t)c * N;
#pragma unroll
    for (int k = 0; k < 4; ++k) {
        int idx = k * 512 + tid;
        int i = idx >> 6, f = idx & 63;
        float num = sm.e.pC[0][i][f] + sm.e.pC[1][i][f] + sm.e.pC[2][i][f] + sm.e.pC[3][i][f];
        numC[(size_t)(ibase + i) * FOUT + f] = num;
        if (f == 0) {
            denC[ibase + i] = sm.e.pD[0][i] + sm.e.pD[1][i] + sm.e.pD[2][i] + sm.e.pD[3][i];
        }
    }
}

// Kernel 3: sum chunk partials, divide, ELU, store.
__global__ __launch_bounds__(256) void gat_combine(
    const float* __restrict__ numP, const float* __restrict__ denP,
    float* __restrict__ out) {
    int idx = blockIdx.x * 256 + threadIdx.x;
    int row = idx >> 6;
    float num = 0.f, den = 0.f;
#pragma unroll
    for (int cc = 0; cc < CSPLIT; ++cc) {
        num += numP[(size_t)cc * N * FOUT + idx];
        den += denP[(size_t)cc * N + row];
    }
    float v = num / den;
    out[idx] = (v > 0.f) ? v : expm1f(v);
}

extern "C" void kernel_launch(void* const* d_in, const int* in_sizes, int n_in,
                              void* d_out, int out_size, void* d_ws, size_t ws_size,
                              hipStream_t stream) {
    const float* h = (const float*)d_in[0];
    const int* adj = (const int*)d_in[1];
    const float* W = (const float*)d_in[2];
    const float* a = (const float*)d_in[3];
    float* out = (float*)d_out;

    char* ws = (char*)d_ws;
    __hip_bfloat16* whT = (__hip_bfloat16*)ws;                       // 1 MB
    float* s_src = (float*)(ws + (size_t)FOUT * N * sizeof(__hip_bfloat16));
    float* s_dst = s_src + N;                                        // +32 KB each
    float* numP = s_dst + N;                                         // 4 MB
    float* denP = numP + (size_t)CSPLIT * N * FOUT;                  // 64 KB
    unsigned int* pk = (unsigned int*)(denP + (size_t)CSPLIT * N);   // 8 MB

    hipLaunchKernelGGL(pack_kernel, dim3(2048), dim3(256), 0, stream, adj, pk);
    hipLaunchKernelGGL(wh_kernel, dim3(N / 4), dim3(256), 0, stream,
                       h, W, a, whT, s_src, s_dst);
    hipLaunchKernelGGL(gat_partial, dim3((N / M) * CSPLIT), dim3(512), 0, stream,
                       pk, whT, s_src, s_dst, numP, denP);
    hipLaunchKernelGGL(gat_combine, dim3(N * FOUT / 256), dim3(256), 0, stream,
                       numP, denP, out);
}